// Round 5
// baseline (627.458 us; speedup 1.0000x reference)
//
#include <hip/hip_runtime.h>
#include <stdint.h>

// Problem constants (SRUCell): L=1024, B=32, IN=1024, D=1024
#define L_   1024
#define B_   32
#define IN_  1024
#define D_   1024
#define M_   (L_ * B_)   // 32768  GEMM rows
#define N4_  (4 * D_)    // 4096   GEMM cols
#define K_   IN_         // 1024   GEMM inner

#define L2E      1.4426950408889634f
#define TWO_L2E  2.8853900817779268f

typedef _Float16 f16x8 __attribute__((ext_vector_type(8)));  // 8 fp16 = 4 VGPRs
typedef float    f32x4 __attribute__((ext_vector_type(4)));

#define GLB(p) (const __attribute__((address_space(1))) void*)(p)
#define LDSP(p) (__attribute__((address_space(3))) void*)(p)

__device__ __forceinline__ unsigned short f2h(float f) {
  _Float16 h = (_Float16)f;  // RNE
  return __builtin_bit_cast(unsigned short, h);
}
__device__ __forceinline__ float h2f(unsigned short b) {
  return (float)__builtin_bit_cast(_Float16, b);
}

// ---------------------------------------------------------------- cvt x -> fp16
__global__ void cvt_x(const float* __restrict__ x, unsigned short* __restrict__ xh) {
  int i = (blockIdx.x * 256 + threadIdx.x) * 4;
  float4 v = *(const float4*)(x + i);
  ushort4 o;
  o.x = f2h(v.x); o.y = f2h(v.y); o.z = f2h(v.z); o.w = f2h(v.w);
  *(ushort4*)(xh + i) = o;
}

// ------------------------------------------- transpose W (K_ x N4_) -> Wt fp16 (N4_ x K_)
// Gate columns n&3==1 (f) and n&3==2 (r) pre-scaled by log2(e) for exp2-domain sigmoid.
__global__ void cvt_wt(const float* __restrict__ W, unsigned short* __restrict__ Wt) {
  __shared__ float t[32][33];  // +1 pad breaks bank conflicts
  int tx = threadIdx.x, ty = threadIdx.y;
  int x0 = blockIdx.x * 32, y0 = blockIdx.y * 32;
  t[ty][tx] = W[(size_t)(y0 + ty) * N4_ + x0 + tx];
  __syncthreads();
  int n = x0 + ty;
  int g = n & 3;
  float s = (g == 1 || g == 2) ? L2E : 1.0f;
  Wt[(size_t)n * K_ + y0 + tx] = f2h(t[tx][ty] * s);
}

// ---------------------------------------------------------------- GEMM (256x256 8-phase)
// 945 TF, MfmaUtil 43%, bank conflicts 0, refcheck'd round 1.

#define BARRIER() do { __builtin_amdgcn_sched_barrier(0); __builtin_amdgcn_s_barrier(); \
                       __builtin_amdgcn_sched_barrier(0); } while (0)
#define VMW8 asm volatile("s_waitcnt vmcnt(8)" ::: "memory")
#define SBAR0 __builtin_amdgcn_sched_barrier(0)

__device__ __forceinline__ void stage_half(const unsigned short* __restrict__ g,
                                           unsigned short* __restrict__ half_,
                                           int rowbase, int ktile, int kk,
                                           int wave, int srow, int skel) {
  const int kt = ktile < 15 ? ktile : 15;  // clamp: keeps loads in-bounds & uniform
  const unsigned short* g0 =
      g + (size_t)(rowbase + wave * 32 + srow) * K_ + kt * 64 + kk * 32 + skel;
  __builtin_amdgcn_global_load_lds(GLB(g0), LDSP(half_ + wave * 1024), 16, 0, 0);
  __builtin_amdgcn_global_load_lds(GLB(g0 + (size_t)16 * K_),
                                   LDSP(half_ + wave * 1024 + 512), 16, 0, 0);
}

__global__ __launch_bounds__(512, 2) void gemm_u(const unsigned short* __restrict__ A,
                                                 const unsigned short* __restrict__ Bt,
                                                 unsigned short* __restrict__ U) {
  __shared__ unsigned short lds[65536];  // 128 KiB

  const int tid  = threadIdx.x;
  const int wave = tid >> 6;   // 0..7
  const int lane = tid & 63;
  const int l15  = lane & 15;
  const int quad = lane >> 4;
  const int wm   = wave >> 2;  // 0..1 (M), 128 rows each
  const int wn   = wave & 3;   // 0..3 (N), 64 cols each

  const int bid = blockIdx.x;
  const int swz = (bid & 7) * 256 + (bid >> 3);
  const int n0  = (swz & 15) * 256;
  const int m0  = (swz >> 4) * 256;

  const int srow = lane >> 2;
  const int skel = ((lane & 3) * 8) ^ ((lane >= 32) ? 16 : 0);
  const int roff = (l15 * 32 + quad * 8) ^ ((l15 >= 8) ? 16 : 0);

#define HA(s, h) (lds + ((s)*2 + (h)) * 8192)
#define HB(s, h) (lds + 32768 + ((s)*2 + (h)) * 8192)

  f32x4 acc[8][4];
#pragma unroll
  for (int i = 0; i < 8; i++)
#pragma unroll
    for (int j = 0; j < 4; j++) acc[i][j] = (f32x4){0.f, 0.f, 0.f, 0.f};

  stage_half(A,  HA(0, 0), m0, 0, 0, wave, srow, skel); SBAR0;
  stage_half(Bt, HB(0, 0), n0, 0, 0, wave, srow, skel); SBAR0;
  stage_half(A,  HA(0, 1), m0, 0, 1, wave, srow, skel); SBAR0;
  stage_half(Bt, HB(0, 1), n0, 0, 1, wave, srow, skel); SBAR0;
  stage_half(A,  HA(1, 0), m0, 1, 0, wave, srow, skel); SBAR0;
  stage_half(Bt, HB(1, 0), n0, 1, 0, wave, srow, skel); SBAR0;
  VMW8;
  BARRIER();

  f16x8 afr[4], bfr[4];

#define PHASE(S, KK, MH, GMAT, LHALF, ROWB, KT, KH, DO_VMW)                        \
  {                                                                                \
    const unsigned short* ha = HA(S, KK);                                          \
    if ((MH) == 0) {                                                               \
      const unsigned short* hb = HB(S, KK);                                        \
      _Pragma("unroll") for (int ni = 0; ni < 4; ++ni)                             \
          bfr[ni] = *(const f16x8*)(hb + (wn * 4 + ni) * 512 + roff);              \
    }                                                                              \
    _Pragma("unroll") for (int mi = 0; mi < 4; ++mi)                               \
        afr[mi] = *(const f16x8*)(ha + (wm * 8 + (MH)*4 + mi) * 512 + roff);       \
    stage_half(GMAT, LHALF, ROWB, KT, KH, wave, srow, skel);                       \
    BARRIER();                                                                     \
    __builtin_amdgcn_s_setprio(1);                                                 \
    _Pragma("unroll") for (int mi = 0; mi < 4; ++mi)                               \
        _Pragma("unroll") for (int ni = 0; ni < 4; ++ni)                           \
            acc[(MH)*4 + mi][ni] = __builtin_amdgcn_mfma_f32_16x16x32_f16(         \
                afr[mi], bfr[ni], acc[(MH)*4 + mi][ni], 0, 0, 0);                  \
    __builtin_amdgcn_s_setprio(0);                                                 \
    if (DO_VMW) VMW8;                                                              \
    BARRIER();                                                                     \
  }

#pragma unroll 1
  for (int it = 0; it < 8; ++it) {
    const int t1 = 2 * it + 1, t2 = 2 * it + 2, t3 = 2 * it + 3;
    PHASE(0, 0, 0, A,  HA(1, 1), m0, t1, 1, 0)
    PHASE(0, 0, 1, Bt, HB(1, 1), n0, t1, 1, 1)
    PHASE(0, 1, 0, A,  HA(0, 0), m0, t2, 0, 0)
    PHASE(0, 1, 1, Bt, HB(0, 0), n0, t2, 0, 1)
    PHASE(1, 0, 0, A,  HA(0, 1), m0, t2, 1, 0)
    PHASE(1, 0, 1, Bt, HB(0, 1), n0, t2, 1, 1)
    PHASE(1, 1, 0, A,  HA(1, 0), m0, t3, 0, 0)
    PHASE(1, 1, 1, Bt, HB(1, 0), n0, t3, 0, 1)
  }
#undef PHASE

#pragma unroll
  for (int mi = 0; mi < 8; ++mi) {
#pragma unroll
    for (int ni = 0; ni < 4; ++ni) {
      const int row = m0 + wm * 128 + mi * 16 + quad * 4;
      const int col = n0 + wn * 64 + ni * 16 + l15;
#pragma unroll
      for (int i = 0; i < 4; ++i)
        U[(size_t)(row + i) * N4_ + col] = f2h(acc[mi][ni][i]);
    }
  }
#undef HA
#undef HB
}

// ---------------------------------------------------------------- sequential scan
// One thread per (b,d) chain; t = b*D_+d. U uint2 index for step l is l*32768 + t.
// Gates arrive pre-scaled by log2(e) (u1', u2'), so sigmoid = rcp(1+exp2(-p)).
// PF=16 prefetch: 16 steps x ~70 cyc covers ~1100 cyc >> 900 cyc HBM latency.
__global__ __launch_bounds__(64) void scan_kernel(const unsigned short* __restrict__ U,
                                                  const float* __restrict__ c0,
                                                  const float* __restrict__ V,
                                                  const float* __restrict__ bias,
                                                  float* __restrict__ out) {
  const int t = blockIdx.x * 64 + threadIdx.x;  // 0..32767
  const int d = t & (D_ - 1);
  float c = c0[t];
  const float vfp = V[d] * L2E, vrp = V[D_ + d] * L2E;
  const float bfp = bias[d] * L2E, brp = bias[D_ + d] * L2E;
  const uint2* Up = (const uint2*)U;  // 4 fp16 gates per uint2

  constexpr int PF = 16;
  uint2 buf[PF];
#pragma unroll
  for (int j = 0; j < PF; j++) buf[j] = Up[(size_t)j * 32768 + t];

#define SRU_STEP(u, l)                                                          \
  {                                                                             \
    const float u0 = h2f((unsigned short)((u).x & 0xffffu));                    \
    const float u1 = h2f((unsigned short)((u).x >> 16)); /* pre-scaled */       \
    const float u2 = h2f((unsigned short)((u).y & 0xffffu)); /* pre-scaled */   \
    const float u3 = h2f((unsigned short)((u).y >> 16));                        \
    const float pf = fmaf(c, vfp, u1 + bfp);                                    \
    const float pr = fmaf(c, vrp, u2 + brp);                                    \
    const float f  = __builtin_amdgcn_rcpf(1.f + __builtin_amdgcn_exp2f(-pf));  \
    const float r  = __builtin_amdgcn_rcpf(1.f + __builtin_amdgcn_exp2f(-pr));  \
    c = fmaf(c - u0, f, u0);                                                    \
    const float q  = __builtin_amdgcn_exp2f(c * TWO_L2E);                       \
    const float th = fmaf(-2.f, __builtin_amdgcn_rcpf(1.f + q), 1.f);           \
    const float h  = fmaf(th - u3, r, u3);                                      \
    __builtin_nontemporal_store(h, out + (size_t)(l) * 32768 + t);              \
  }

#pragma unroll 1
  for (int l0 = 0; l0 < L_ - PF; l0 += PF) {
#pragma unroll
    for (int j = 0; j < PF; j++) {
      uint2 u = buf[j];
      buf[j] = Up[(size_t)(l0 + j + PF) * 32768 + t];  // unconditional prefetch
      SRU_STEP(u, l0 + j);
    }
  }
  // tail: last PF steps, no prefetch
#pragma unroll
  for (int j = 0; j < PF; j++) {
    uint2 u = buf[j];
    SRU_STEP(u, L_ - PF + j);
  }
#undef SRU_STEP

  out[(size_t)L_ * 32768 + t] = c;  // c_last appended after h
}

extern "C" void kernel_launch(void* const* d_in, const int* in_sizes, int n_in,
                              void* d_out, int out_size, void* d_ws, size_t ws_size,
                              hipStream_t stream) {
  const float* x    = (const float*)d_in[0];
  const float* c0   = (const float*)d_in[1];
  const float* W    = (const float*)d_in[2];
  const float* V    = (const float*)d_in[3];
  const float* bias = (const float*)d_in[4];
  float* out = (float*)d_out;

  uint8_t* ws = (uint8_t*)d_ws;
  unsigned short* Xh = (unsigned short*)ws;                          // 64 MB fp16 x
  unsigned short* Wt = (unsigned short*)(ws + ((size_t)64 << 20));   // 8 MB fp16 W^T
  unsigned short* U  = (unsigned short*)(ws + ((size_t)72 << 20));   // 256 MB fp16 U
  // total workspace: 328 MB

  cvt_x<<<(M_ * K_) / 1024, 256, 0, stream>>>(x, Xh);
  cvt_wt<<<dim3(N4_ / 32, K_ / 32), dim3(32, 32), 0, stream>>>(W, Wt);
  gemm_u<<<2048, 512, 0, stream>>>(Xh, Wt, U);
  scan_kernel<<<(B_ * D_) / 64, 64, 0, stream>>>(U, c0, V, bias, out);
}

// Round 6
// 598.034 us; speedup vs baseline: 1.0492x; 1.0492x over previous
//
#include <hip/hip_runtime.h>
#include <stdint.h>

// Problem constants (SRUCell): L=1024, B=32, IN=1024, D=1024
#define L_   1024
#define B_   32
#define IN_  1024
#define D_   1024
#define M_   (L_ * B_)   // 32768  GEMM rows
#define N4_  (4 * D_)    // 4096   GEMM cols
#define K_   IN_         // 1024   GEMM inner

#define L2E      1.4426950408889634f
#define TWO_L2E  2.8853900817779268f

typedef _Float16 f16x8 __attribute__((ext_vector_type(8)));  // 8 fp16 = 4 VGPRs
typedef float    f32x4 __attribute__((ext_vector_type(4)));

#define GLB(p) (const __attribute__((address_space(1))) void*)(p)
#define LDSP(p) (__attribute__((address_space(3))) void*)(p)

__device__ __forceinline__ unsigned short f2h(float f) {
  _Float16 h = (_Float16)f;  // RNE
  return __builtin_bit_cast(unsigned short, h);
}
__device__ __forceinline__ float h2f(unsigned short b) {
  return (float)__builtin_bit_cast(_Float16, b);
}

// ---------------------------------------------------------------- cvt x -> fp16
__global__ void cvt_x(const float* __restrict__ x, unsigned short* __restrict__ xh) {
  int i = (blockIdx.x * 256 + threadIdx.x) * 4;
  float4 v = *(const float4*)(x + i);
  ushort4 o;
  o.x = f2h(v.x); o.y = f2h(v.y); o.z = f2h(v.z); o.w = f2h(v.w);
  *(ushort4*)(xh + i) = o;
}

// ------------------------------------------- transpose W (K_ x N4_) -> Wt fp16 (N4_ x K_)
// Gate columns n&3==1 (f) and n&3==2 (r) pre-scaled by log2(e) for exp2-domain sigmoid.
__global__ void cvt_wt(const float* __restrict__ W, unsigned short* __restrict__ Wt) {
  __shared__ float t[32][33];  // +1 pad breaks bank conflicts
  int tx = threadIdx.x, ty = threadIdx.y;
  int x0 = blockIdx.x * 32, y0 = blockIdx.y * 32;
  t[ty][tx] = W[(size_t)(y0 + ty) * N4_ + x0 + tx];
  __syncthreads();
  int n = x0 + ty;
  int g = n & 3;
  float s = (g == 1 || g == 2) ? L2E : 1.0f;
  Wt[(size_t)n * K_ + y0 + tx] = f2h(t[tx][ty] * s);
}

// ---------------------------------------------------------------- GEMM (256x256 8-phase)
// Sync schedule UNCHANGED (945 TF, MfmaUtil 43%, conflicts 0, refcheck'd rounds 1&5).
// Only the epilogue's store ADDRESS changed: U is now laid out step-paired,
//   u16 index(m,n) = ((l>>1)*32768 + t)*8 + (l&1)*4 + g
//   with l=m>>5, b=m&31, d=n>>2, g=n&3, t=b*D+d
// so the scan can read 2 steps (16 B) per load.

#define BARRIER() do { __builtin_amdgcn_sched_barrier(0); __builtin_amdgcn_s_barrier(); \
                       __builtin_amdgcn_sched_barrier(0); } while (0)
#define VMW8 asm volatile("s_waitcnt vmcnt(8)" ::: "memory")
#define SBAR0 __builtin_amdgcn_sched_barrier(0)

__device__ __forceinline__ void stage_half(const unsigned short* __restrict__ g,
                                           unsigned short* __restrict__ half_,
                                           int rowbase, int ktile, int kk,
                                           int wave, int srow, int skel) {
  const int kt = ktile < 15 ? ktile : 15;  // clamp: keeps loads in-bounds & uniform
  const unsigned short* g0 =
      g + (size_t)(rowbase + wave * 32 + srow) * K_ + kt * 64 + kk * 32 + skel;
  __builtin_amdgcn_global_load_lds(GLB(g0), LDSP(half_ + wave * 1024), 16, 0, 0);
  __builtin_amdgcn_global_load_lds(GLB(g0 + (size_t)16 * K_),
                                   LDSP(half_ + wave * 1024 + 512), 16, 0, 0);
}

__global__ __launch_bounds__(512, 2) void gemm_u(const unsigned short* __restrict__ A,
                                                 const unsigned short* __restrict__ Bt,
                                                 unsigned short* __restrict__ U) {
  __shared__ unsigned short lds[65536];  // 128 KiB

  const int tid  = threadIdx.x;
  const int wave = tid >> 6;   // 0..7
  const int lane = tid & 63;
  const int l15  = lane & 15;
  const int quad = lane >> 4;
  const int wm   = wave >> 2;  // 0..1 (M), 128 rows each
  const int wn   = wave & 3;   // 0..3 (N), 64 cols each

  const int bid = blockIdx.x;
  const int swz = (bid & 7) * 256 + (bid >> 3);
  const int n0  = (swz & 15) * 256;
  const int m0  = (swz >> 4) * 256;

  const int srow = lane >> 2;
  const int skel = ((lane & 3) * 8) ^ ((lane >= 32) ? 16 : 0);
  const int roff = (l15 * 32 + quad * 8) ^ ((l15 >= 8) ? 16 : 0);

#define HA(s, h) (lds + ((s)*2 + (h)) * 8192)
#define HB(s, h) (lds + 32768 + ((s)*2 + (h)) * 8192)

  f32x4 acc[8][4];
#pragma unroll
  for (int i = 0; i < 8; i++)
#pragma unroll
    for (int j = 0; j < 4; j++) acc[i][j] = (f32x4){0.f, 0.f, 0.f, 0.f};

  stage_half(A,  HA(0, 0), m0, 0, 0, wave, srow, skel); SBAR0;
  stage_half(Bt, HB(0, 0), n0, 0, 0, wave, srow, skel); SBAR0;
  stage_half(A,  HA(0, 1), m0, 0, 1, wave, srow, skel); SBAR0;
  stage_half(Bt, HB(0, 1), n0, 0, 1, wave, srow, skel); SBAR0;
  stage_half(A,  HA(1, 0), m0, 1, 0, wave, srow, skel); SBAR0;
  stage_half(Bt, HB(1, 0), n0, 1, 0, wave, srow, skel); SBAR0;
  VMW8;
  BARRIER();

  f16x8 afr[4], bfr[4];

#define PHASE(S, KK, MH, GMAT, LHALF, ROWB, KT, KH, DO_VMW)                        \
  {                                                                                \
    const unsigned short* ha = HA(S, KK);                                          \
    if ((MH) == 0) {                                                               \
      const unsigned short* hb = HB(S, KK);                                        \
      _Pragma("unroll") for (int ni = 0; ni < 4; ++ni)                             \
          bfr[ni] = *(const f16x8*)(hb + (wn * 4 + ni) * 512 + roff);              \
    }                                                                              \
    _Pragma("unroll") for (int mi = 0; mi < 4; ++mi)                               \
        afr[mi] = *(const f16x8*)(ha + (wm * 8 + (MH)*4 + mi) * 512 + roff);       \
    stage_half(GMAT, LHALF, ROWB, KT, KH, wave, srow, skel);                       \
    BARRIER();                                                                     \
    __builtin_amdgcn_s_setprio(1);                                                 \
    _Pragma("unroll") for (int mi = 0; mi < 4; ++mi)                               \
        _Pragma("unroll") for (int ni = 0; ni < 4; ++ni)                           \
            acc[(MH)*4 + mi][ni] = __builtin_amdgcn_mfma_f32_16x16x32_f16(         \
                afr[mi], bfr[ni], acc[(MH)*4 + mi][ni], 0, 0, 0);                  \
    __builtin_amdgcn_s_setprio(0);                                                 \
    if (DO_VMW) VMW8;                                                              \
    BARRIER();                                                                     \
  }

#pragma unroll 1
  for (int it = 0; it < 8; ++it) {
    const int t1 = 2 * it + 1, t2 = 2 * it + 2, t3 = 2 * it + 3;
    PHASE(0, 0, 0, A,  HA(1, 1), m0, t1, 1, 0)
    PHASE(0, 0, 1, Bt, HB(1, 1), n0, t1, 1, 1)
    PHASE(0, 1, 0, A,  HA(0, 0), m0, t2, 0, 0)
    PHASE(0, 1, 1, Bt, HB(0, 0), n0, t2, 0, 1)
    PHASE(1, 0, 0, A,  HA(0, 1), m0, t2, 1, 0)
    PHASE(1, 0, 1, Bt, HB(0, 1), n0, t2, 1, 1)
    PHASE(1, 1, 0, A,  HA(1, 0), m0, t3, 0, 0)
    PHASE(1, 1, 1, Bt, HB(1, 0), n0, t3, 0, 1)
  }
#undef PHASE

  // epilogue: C/D layout col = lane&15 (N), row = quad*4 + reg (M).
  // Store into the step-paired U layout (see header comment).
#pragma unroll
  for (int mi = 0; mi < 8; ++mi) {
#pragma unroll
    for (int ni = 0; ni < 4; ++ni) {
      const int row = m0 + wm * 128 + mi * 16 + quad * 4;
      const int col = n0 + wn * 64 + ni * 16 + l15;
      const int d   = col >> 2;
      const int g   = col & 3;
#pragma unroll
      for (int i = 0; i < 4; ++i) {
        const int m = row + i;
        const int l = m >> 5;
        const int b = m & 31;
        const int t = b * D_ + d;
        const size_t idx =
            (((size_t)(l >> 1) * 32768 + t) << 3) + (size_t)((l & 1) * 4 + g);
        U[idx] = f2h(acc[mi][ni][i]);
      }
    }
  }
#undef HA
#undef HB
}

// ---------------------------------------------------------------- sequential scan
// One thread per (b,d) chain. U step-paired: one uint4 (16 B) = 2 steps x 4 gates.
// PF=16 uint4 = 32 steps in flight = 16 KB/wave, 8 MB chip-wide (2x round-1),
// with HALF the load instructions. Same 64-VGPR buffer footprint as the
// 3x-harness-verified PF=16 kernel.
__global__ __launch_bounds__(64) void scan_kernel(const unsigned short* __restrict__ U,
                                                  const float* __restrict__ c0,
                                                  const float* __restrict__ V,
                                                  const float* __restrict__ bias,
                                                  float* __restrict__ out) {
  const int t = blockIdx.x * 64 + threadIdx.x;  // 0..32767
  const int d = t & (D_ - 1);
  float c = c0[t];
  const float vfp = V[d] * L2E, vrp = V[D_ + d] * L2E;
  const float bfp = bias[d] * L2E, brp = bias[D_ + d] * L2E;
  const uint4* Up = (const uint4*)U;  // 2 steps (8 fp16) per uint4

  constexpr int PF = 16;  // pairs; 32 steps
  uint4 buf[PF];
#pragma unroll
  for (int j = 0; j < PF; j++) buf[j] = Up[(size_t)j * 32768 + t];

#define SRU_STEP(w0, w1, l)                                                     \
  {                                                                             \
    const float u0 = h2f((unsigned short)((w0) & 0xffffu));                     \
    const float u1 = h2f((unsigned short)((w0) >> 16)); /* pre-scaled */        \
    const float u2 = h2f((unsigned short)((w1) & 0xffffu)); /* pre-scaled */    \
    const float u3 = h2f((unsigned short)((w1) >> 16));                         \
    const float pf = fmaf(c, vfp, u1 + bfp);                                    \
    const float pr = fmaf(c, vrp, u2 + brp);                                    \
    const float f  = __builtin_amdgcn_rcpf(1.f + __builtin_amdgcn_exp2f(-pf));  \
    const float r  = __builtin_amdgcn_rcpf(1.f + __builtin_amdgcn_exp2f(-pr));  \
    c = fmaf(c - u0, f, u0);                                                    \
    const float q  = __builtin_amdgcn_exp2f(c * TWO_L2E);                       \
    const float th = fmaf(-2.f, __builtin_amdgcn_rcpf(1.f + q), 1.f);           \
    const float h  = fmaf(th - u3, r, u3);                                      \
    __builtin_nontemporal_store(h, out + (size_t)(l) * 32768 + t);              \
  }

#pragma unroll 1
  for (int p0 = 0; p0 < 512 - PF; p0 += PF) {
#pragma unroll
    for (int j = 0; j < PF; j++) {
      uint4 u = buf[j];
      buf[j] = Up[(size_t)(p0 + j + PF) * 32768 + t];  // unconditional prefetch
      const int l = 2 * (p0 + j);
      SRU_STEP(u.x, u.y, l);
      SRU_STEP(u.z, u.w, l + 1);
    }
  }
  // tail: last PF pairs, no prefetch
#pragma unroll
  for (int j = 0; j < PF; j++) {
    uint4 u = buf[j];
    const int l = 2 * (512 - PF + j);
    SRU_STEP(u.x, u.y, l);
    SRU_STEP(u.z, u.w, l + 1);
  }
#undef SRU_STEP

  out[(size_t)L_ * 32768 + t] = c;  // c_last appended after h
}

extern "C" void kernel_launch(void* const* d_in, const int* in_sizes, int n_in,
                              void* d_out, int out_size, void* d_ws, size_t ws_size,
                              hipStream_t stream) {
  const float* x    = (const float*)d_in[0];
  const float* c0   = (const float*)d_in[1];
  const float* W    = (const float*)d_in[2];
  const float* V    = (const float*)d_in[3];
  const float* bias = (const float*)d_in[4];
  float* out = (float*)d_out;

  uint8_t* ws = (uint8_t*)d_ws;
  unsigned short* Xh = (unsigned short*)ws;                          // 64 MB fp16 x
  unsigned short* Wt = (unsigned short*)(ws + ((size_t)64 << 20));   // 8 MB fp16 W^T
  unsigned short* U  = (unsigned short*)(ws + ((size_t)72 << 20));   // 256 MB fp16 U
  // total workspace: 328 MB

  cvt_x<<<(M_ * K_) / 1024, 256, 0, stream>>>(x, Xh);
  cvt_wt<<<dim3(N4_ / 32, K_ / 32), dim3(32, 32), 0, stream>>>(W, Wt);
  gemm_u<<<2048, 512, 0, stream>>>(Xh, Wt, U);
  scan_kernel<<<(B_ * D_) / 64, 64, 0, stream>>>(U, c0, V, bias, out);
}